// Round 9
// baseline (199.203 us; speedup 1.0000x reference)
//
#include <hip/hip_runtime.h>
#include <math.h>

#define EMBED   64
#define HIDDEN  256
#define SEQ     200
#define SEQP    208           // padded to 13 s-tiles of 16
#define MT      13
#define HROW    80            // fp8 h row stride in bytes (5x16B units: bank spread, 16B aligned)
#define HHALF   (SEQP * HROW) // 16640 bytes per array (h / h*t)

typedef _Float16 f16x8 __attribute__((ext_vector_type(8)));
typedef float    f32x4 __attribute__((ext_vector_type(4)));
typedef float    f32x2 __attribute__((ext_vector_type(2)));
typedef int      i32x8 __attribute__((ext_vector_type(8)));

// ---------------- ws layout ----------------
// [0  , 32K) fragA8 : fp8 A-frags (16x16x128) of attention weights, per (tile,lane) 32 B:
//            lane(m=n&15, q): k = q*32+j; k<64 -> 16*(W0+W2)[k][n]; k>=64 -> 16*W3[k-64][n]
// [32K, 64K) fragB28: fp8 A-frags (16x16x128) of 16*mlp_w1 (k = q*32+j over [interest||t])
// [64K, 96K) fragDt : f16 A-frags (16x16x32) of (W1-W2)^T for the c-fold
__global__ void din_precompute(const float* __restrict__ attn_w1,
                               const float* __restrict__ mlp_w1,
                               uint4* __restrict__ fragA8,
                               uint4* __restrict__ fragB28,
                               _Float16* __restrict__ fragDt) {
  const int gid = blockIdx.x * 256 + threadIdx.x;   // [0, 4096)
  if (gid < 2048) {                                 // fragA8 / fragB28
    const bool head = gid >= 1024;
    const int g = gid & 1023;
    const int tile = g >> 6, lane = g & 63;
    const int n = tile * 16 + (lane & 15);
    const int q = lane >> 4;
    float v[32];
    #pragma unroll
    for (int j = 0; j < 32; ++j) {
      const int k = q * 32 + j;                     // [0,128)
      if (head) {
        v[j] = 16.0f * mlp_w1[k * HIDDEN + n];
      } else {
        if (k < 64) v[j] = 16.0f * (attn_w1[k * HIDDEN + n] + attn_w1[(128 + k) * HIDDEN + n]);
        else        v[j] = 16.0f * attn_w1[(192 + (k - 64)) * HIDDEN + n];
      }
    }
    unsigned d[8];
    #pragma unroll
    for (int w = 0; w < 8; ++w) {
      int pk = __builtin_amdgcn_cvt_pk_fp8_f32(v[4 * w + 0], v[4 * w + 1], 0, false);
      pk     = __builtin_amdgcn_cvt_pk_fp8_f32(v[4 * w + 2], v[4 * w + 3], pk, true);
      d[w] = (unsigned)pk;
    }
    uint4* dst = (head ? fragB28 : fragA8) + (tile * 64 + lane) * 2;
    dst[0] = uint4{d[0], d[1], d[2], d[3]};
    dst[1] = uint4{d[4], d[5], d[6], d[7]};
  } else {                                          // fragDt (f16 16x16x32 A-frags)
    const int g = gid - 2048;
    const int i = g >> 7, rem = g & 127, kc = rem >> 6, lane = rem & 63;
    const int n = i * 16 + (lane & 15);
    const int kb = kc * 32 + (lane >> 4) * 8;
    #pragma unroll
    for (int j = 0; j < 8; ++j)
      fragDt[g * 8 + j] = (_Float16)(attn_w1[(64 + kb + j) * HIDDEN + n]
                                   - attn_w1[(128 + kb + j) * HIDDEN + n]);
  }
}

// ---------------- single fused kernel: one block (512 thr, 8 waves) per row ----------------
__global__ __launch_bounds__(512, 8)
void din_fused_kernel(const int* __restrict__ user_hist,
                      const int* __restrict__ target_item,
                      const float* __restrict__ user_emb,
                      const float* __restrict__ item_emb,
                      const float* __restrict__ attn_b1,
                      const float* __restrict__ attn_w2,
                      const float* __restrict__ mlp_b1,
                      const float* __restrict__ mlp_w2,
                      const float* __restrict__ mlp_b2,
                      const uint4* __restrict__ fragA8,
                      const uint4* __restrict__ fragB28,
                      const _Float16* __restrict__ fragDt,
                      float* __restrict__ out)
{
  // Hb8[0..HHALF): fp8(16*h), row-contiguous: byte (s*HROW + k), k in [0,64)
  // Hb8[HHALF..):  fp8(16*h*t), same layout (k-blocks 64..127 of the GEMM)
  __shared__ __align__(16) unsigned char Hb8[2 * HHALF];  // 33280 B
  __shared__ float t32[EMBED];                            // 256
  __shared__ __align__(16) _Float16 t16[EMBED];           // 128
  __shared__ __align__(16) unsigned char xin8[128];       // head B: [0,64)=fp8(16*interest), [64,128)=fp8(16*t)
  __shared__ int   histL[SEQP];                           // 832
  __shared__ float logits[SEQP];                          // 832
  __shared__ float weights[SEQP];                         // 832
  __shared__ float pool[8][EMBED];                        // 2048
  __shared__ float red[16];                               // 64
  // total ~38.4 KB -> 4 blocks/CU

  const int b    = blockIdx.x;
  const int tid  = threadIdx.x;
  const int lane = tid & 63;
  const int wave = tid >> 6;
  const int m    = lane & 15;
  const int quad = lane >> 4;

  // ---- phase 0: target embedding (f32/f16/fp8) + hist staging + zero logits ----
  const int tgt = target_item[b];
  if (tid < EMBED) {
    const float v = item_emb[tgt * EMBED + tid];
    t32[tid] = v;
    t16[tid] = (_Float16)v;
  }
  if (tid < 32) {
    const float v0 = 16.0f * item_emb[tgt * EMBED + 2 * tid];
    const float v1 = 16.0f * item_emb[tgt * EMBED + 2 * tid + 1];
    const int pk = __builtin_amdgcn_cvt_pk_fp8_f32(v0, v1, 0, false);
    *(short*)&xin8[64 + 2 * tid] = (short)(pk & 0xffff);
  }
  if (tid < SEQP) {
    histL[tid]  = (tid < SEQ) ? user_hist[b * SEQ + tid] : 0;
    logits[tid] = 0.0f;
  }
  __syncthreads();

  // ---- phase 1: gather h -> fp8(16h) and fp8(16h*t) rows ----
  for (int slot = tid; slot < MT * 2 * 64; slot += 512) {
    const int ln = slot & 63, kcomb = slot >> 6;
    const int st = kcomb >> 1, kc = kcomb & 1;
    const int s = st * 16 + (ln & 15);
    const int kb = kc * 32 + (ln >> 4) * 8;
    const int off = s * HROW + kb;
    if (s < SEQ) {
      const float4* src = reinterpret_cast<const float4*>(&user_emb[histL[s] * EMBED + kb]);
      float4 x = src[0], y = src[1];
      x.x *= 16.f; x.y *= 16.f; x.z *= 16.f; x.w *= 16.f;
      y.x *= 16.f; y.y *= 16.f; y.z *= 16.f; y.w *= 16.f;
      int lo = __builtin_amdgcn_cvt_pk_fp8_f32(x.x, x.y, 0, false);
      lo     = __builtin_amdgcn_cvt_pk_fp8_f32(x.z, x.w, lo, true);
      int hi = __builtin_amdgcn_cvt_pk_fp8_f32(y.x, y.y, 0, false);
      hi     = __builtin_amdgcn_cvt_pk_fp8_f32(y.z, y.w, hi, true);
      const float4 ta = *reinterpret_cast<const float4*>(&t32[kb]);
      const float4 tb = *reinterpret_cast<const float4*>(&t32[kb + 4]);
      int lo2 = __builtin_amdgcn_cvt_pk_fp8_f32(x.x * ta.x, x.y * ta.y, 0, false);
      lo2     = __builtin_amdgcn_cvt_pk_fp8_f32(x.z * ta.z, x.w * ta.w, lo2, true);
      int hi2 = __builtin_amdgcn_cvt_pk_fp8_f32(y.x * tb.x, y.y * tb.y, 0, false);
      hi2     = __builtin_amdgcn_cvt_pk_fp8_f32(y.z * tb.z, y.w * tb.w, hi2, true);
      *(uint2*)&Hb8[off]         = uint2{(unsigned)lo,  (unsigned)hi};
      *(uint2*)&Hb8[HHALF + off] = uint2{(unsigned)lo2, (unsigned)hi2};
    } else {
      *(uint2*)&Hb8[off]         = uint2{0u, 0u};
      *(uint2*)&Hb8[HHALF + off] = uint2{0u, 0u};
    }
  }

  // ---- A-frags for attention GEMM (global, precomputed) ----
  i32x8 A8[2];
  #pragma unroll
  for (int i = 0; i < 2; ++i) {
    const uint4 a0 = fragA8[((2 * wave + i) * 64 + lane) * 2 + 0];
    const uint4 a1 = fragA8[((2 * wave + i) * 64 + lane) * 2 + 1];
    A8[i] = i32x8{(int)a0.x, (int)a0.y, (int)a0.z, (int)a0.w,
                  (int)a1.x, (int)a1.y, (int)a1.z, (int)a1.w};
  }
  __syncthreads();

  // ---- phase 2: c-fold via f16 MFMA: c[n] = b1[n] + t.(W1-W2)[:,n] ----
  const f16x8 tv0 = *reinterpret_cast<const f16x8*>(&t16[quad * 8]);
  const f16x8 tv1 = *reinterpret_cast<const f16x8*>(&t16[32 + quad * 8]);
  float cn[2][4], w2n[2][4];
  #pragma unroll
  for (int i = 0; i < 2; ++i) {
    const int tile = 2 * wave + i;
    const f16x8 d0 = reinterpret_cast<const f16x8*>(fragDt)[(tile * 2 + 0) * 64 + lane];
    const f16x8 d1 = reinterpret_cast<const f16x8*>(fragDt)[(tile * 2 + 1) * 64 + lane];
    f32x4 acc = {0.f, 0.f, 0.f, 0.f};
    acc = __builtin_amdgcn_mfma_f32_16x16x32_f16(d0, tv0, acc, 0, 0, 0);
    acc = __builtin_amdgcn_mfma_f32_16x16x32_f16(d1, tv1, acc, 0, 0, 0);
    const int nb = tile * 16 + quad * 4;
    const float4 b1v = *reinterpret_cast<const float4*>(&attn_b1[nb]);
    const float4 w2v = *reinterpret_cast<const float4*>(&attn_w2[nb]);
    cn[i][0] = b1v.x + acc[0];  cn[i][1] = b1v.y + acc[1];
    cn[i][2] = b1v.z + acc[2];  cn[i][3] = b1v.w + acc[3];
    w2n[i][0] = w2v.x; w2n[i][1] = w2v.y; w2n[i][2] = w2v.z; w2n[i][3] = w2v.w;
  }

  // ---- phase 3: K=128 MX-fp8 MFMA GEMM (H^T); 2 mfma_scale per s-tile per wave ----
  // B lane (col=s at m, quad q): 32 contiguous k-bytes: q<2 -> h-half (q&1)*32,
  // q>=2 -> (h*t)-half. scale_a = 2^-8 per block cancels the 16*16 range scaling.
  {
    const unsigned char* hb = Hb8 + (quad >> 1) * HHALF + (quad & 1) * 32 + m * HROW;
    for (int st = 0; st < MT; ++st) {
      const uint4 b0 = *reinterpret_cast<const uint4*>(hb + st * 16 * HROW);
      const uint4 b1 = *reinterpret_cast<const uint4*>(hb + st * 16 * HROW + 16);
      const i32x8 B8 = i32x8{(int)b0.x, (int)b0.y, (int)b0.z, (int)b0.w,
                             (int)b1.x, (int)b1.y, (int)b1.z, (int)b1.w};
      float lg = 0.f;
      #pragma unroll
      for (int i = 0; i < 2; ++i) {
        f32x4 acc = {cn[i][0], cn[i][1], cn[i][2], cn[i][3]};
        acc = __builtin_amdgcn_mfma_scale_f32_16x16x128_f8f6f4(
                  A8[i], B8, acc, 0, 0, 0, 0x77777777, 0, 0x7F7F7F7F);
        lg += fmaxf(acc[0], 0.0f) * w2n[i][0];
        lg += fmaxf(acc[1], 0.0f) * w2n[i][1];
        lg += fmaxf(acc[2], 0.0f) * w2n[i][2];
        lg += fmaxf(acc[3], 0.0f) * w2n[i][3];
      }
      lg += __shfl_xor(lg, 16, 64);
      lg += __shfl_xor(lg, 32, 64);
      if (lane < 16) atomicAdd(&logits[st * 16 + lane], lg);
    }
  }
  __syncthreads();

  // ---- phase 4: softmax over SEQ on waves 0-3 (attn_b2 cancels) ----
  float v = -INFINITY, e = 0.0f;
  if (wave < 4) {
    if (tid < SEQ) v = logits[tid];
    float mx = v;
    #pragma unroll
    for (int off = 32; off; off >>= 1) mx = fmaxf(mx, __shfl_xor(mx, off, 64));
    if (lane == 0) red[wave] = mx;
  }
  __syncthreads();
  if (wave < 4) {
    const float mx = fmaxf(fmaxf(red[0], red[1]), fmaxf(red[2], red[3]));
    e = (tid < SEQ) ? expf(v - mx) : 0.0f;
    float ssum = e;
    #pragma unroll
    for (int off = 32; off; off >>= 1) ssum += __shfl_xor(ssum, off, 64);
    if (lane == 0) red[4 + wave] = ssum;
  }
  __syncthreads();
  if (wave < 4) {
    const float tot = red[4] + red[5] + red[6] + red[7];
    if (tid < SEQP) weights[tid] = (tid < SEQ) ? e / tot : 0.0f;
  }
  __syncthreads();

  // ---- phase 5: weighted interest pooling (reads fp8 h rows, dword per lane) ----
  {
    const int kd = m;                       // k-dword index: bytes 4kd..4kd+4
    const int s0 = wave * 4 + quad;         // 32 parallel s-slots
    float pk4[4] = {0.f, 0.f, 0.f, 0.f};
    for (int s = s0; s < SEQ; s += 32) {
      const float wt = weights[s];
      const unsigned hv = *reinterpret_cast<const unsigned*>(&Hb8[s * HROW + kd * 4]);
      const f32x2 f0 = __builtin_amdgcn_cvt_pk_f32_fp8((int)hv, false);
      const f32x2 f1 = __builtin_amdgcn_cvt_pk_f32_fp8((int)hv, true);
      pk4[0] += wt * f0.x;  pk4[1] += wt * f0.y;
      pk4[2] += wt * f1.x;  pk4[3] += wt * f1.y;
    }
    #pragma unroll
    for (int j = 0; j < 4; ++j) {
      float p = pk4[j];
      p += __shfl_xor(p, 16, 64);
      p += __shfl_xor(p, 32, 64);
      pk4[j] = p;
    }
    if (quad == 0)
      *reinterpret_cast<float4*>(&pool[wave][kd * 4]) = float4{pk4[0], pk4[1], pk4[2], pk4[3]};
  }
  __syncthreads();
  if (tid < 32) {                           // interest (already 16x-scaled) -> fp8
    const int k0 = 2 * tid;
    float a = 0.f, c = 0.f;
    #pragma unroll
    for (int w = 0; w < 8; ++w) { a += pool[w][k0]; c += pool[w][k0 + 1]; }
    const int pk = __builtin_amdgcn_cvt_pk_fp8_f32(a, c, 0, false);
    *(short*)&xin8[k0] = (short)(pk & 0xffff);
  }
  __syncthreads();

  // ---- phase 6: prediction head via one K=128 MX-fp8 MFMA per tile ----
  {
    i32x8 A2[2];
    #pragma unroll
    for (int i = 0; i < 2; ++i) {
      const uint4 a0 = fragB28[((2 * wave + i) * 64 + lane) * 2 + 0];
      const uint4 a1 = fragB28[((2 * wave + i) * 64 + lane) * 2 + 1];
      A2[i] = i32x8{(int)a0.x, (int)a0.y, (int)a0.z, (int)a0.w,
                    (int)a1.x, (int)a1.y, (int)a1.z, (int)a1.w};
    }
    const int xo = (quad >> 1) * 64 + (quad & 1) * 32;   // [interest(64) || t(64)]
    const uint4 b0 = *reinterpret_cast<const uint4*>(&xin8[xo]);
    const uint4 b1 = *reinterpret_cast<const uint4*>(&xin8[xo + 16]);
    const i32x8 B2 = i32x8{(int)b0.x, (int)b0.y, (int)b0.z, (int)b0.w,
                           (int)b1.x, (int)b1.y, (int)b1.z, (int)b1.w};
    float z = 0.f;
    #pragma unroll
    for (int i = 0; i < 2; ++i) {
      const int nb = (2 * wave + i) * 16 + quad * 4;
      const float4 bb = *reinterpret_cast<const float4*>(&mlp_b1[nb]);
      const float4 ww = *reinterpret_cast<const float4*>(&mlp_w2[nb]);
      f32x4 acc = {bb.x, bb.y, bb.z, bb.w};
      acc = __builtin_amdgcn_mfma_scale_f32_16x16x128_f8f6f4(
                A2[i], B2, acc, 0, 0, 0, 0x77777777, 0, 0x7F7F7F7F);
      z += fmaxf(acc[0], 0.0f) * ww.x;
      z += fmaxf(acc[1], 0.0f) * ww.y;
      z += fmaxf(acc[2], 0.0f) * ww.z;
      z += fmaxf(acc[3], 0.0f) * ww.w;
    }
    z += __shfl_xor(z, 16, 64);
    z += __shfl_xor(z, 32, 64);
    if (lane == 0) red[wave] = z;
  }
  __syncthreads();
  if (tid == 0) {
    const float zz = red[0] + red[1] + red[2] + red[3]
                   + red[4] + red[5] + red[6] + red[7] + mlp_b2[0];
    out[b] = 1.0f / (1.0f + expf(-zz));
  }
}

extern "C" void kernel_launch(void* const* d_in, const int* in_sizes, int n_in,
                              void* d_out, int out_size, void* d_ws, size_t ws_size,
                              hipStream_t stream) {
  const int*   user_hist   = (const int*)  d_in[0];
  const int*   target_item = (const int*)  d_in[1];
  const float* user_emb    = (const float*)d_in[2];
  const float* item_emb    = (const float*)d_in[3];
  const float* attn_w1     = (const float*)d_in[4];
  const float* attn_b1     = (const float*)d_in[5];
  const float* attn_w2     = (const float*)d_in[6];
  // d_in[7] = attn_b2: constant shift on logits -> cancels in softmax
  const float* mlp_w1      = (const float*)d_in[8];
  const float* mlp_b1      = (const float*)d_in[9];
  const float* mlp_w2      = (const float*)d_in[10];
  const float* mlp_b2      = (const float*)d_in[11];
  float* out = (float*)d_out;

  uint4*    fragA8  = (uint4*)d_ws;                          // 32 KB
  uint4*    fragB28 = (uint4*)((char*)d_ws + 32768);         // 32 KB
  _Float16* fragDt  = (_Float16*)((char*)d_ws + 65536);      // 32 KB

  din_precompute<<<16, 256, 0, stream>>>(attn_w1, mlp_w1, fragA8, fragB28, fragDt);

  const int batch = in_sizes[1];
  din_fused_kernel<<<batch, 512, 0, stream>>>(
      user_hist, target_item, user_emb, item_emb,
      attn_b1, attn_w2, mlp_b1, mlp_w2, mlp_b2,
      fragA8, fragB28, fragDt, out);
}

// Round 10
// 176.003 us; speedup vs baseline: 1.1318x; 1.1318x over previous
//
#include <hip/hip_runtime.h>
#include <math.h>

#define EMBED   64
#define HIDDEN  256
#define SEQ     200
#define SEQP    208          // padded to 13 s-tiles of 16
#define MT      13
#define VOCAB   100000

typedef _Float16 f16x8  __attribute__((ext_vector_type(8)));
typedef float    f32x4  __attribute__((ext_vector_type(4)));
typedef float    f32x2  __attribute__((ext_vector_type(2)));

// ---------------- ws layout ----------------
// [0   , 16K ) fragB8 : fp8 A-frags of 16*(W0+W2)  [tile 16][kc 2][lane 64] x 8B
// [16K , 48K ) fragW3 : f16 A-frags of 16*W3       [tile 16][kc 2][lane 64] x f16x8
// [48K , 80K ) fragDt : f16 A-frags of (W1-W2)^T   [tile 16][kc 2][lane 64] x f16x8
// [80K , 144K) fragB2 : f16 A-frags of mlp_w1      [tile 16][kc 4][lane 64] x f16x8
// [144K, 144K+6.4M) emb8: fp8(16*user_emb), row-major 64 B/vocab row (L3-resident)
__global__ void din_precompute(const float* __restrict__ attn_w1,
                               const float* __restrict__ mlp_w1,
                               uint2* __restrict__ fragB8,
                               _Float16* __restrict__ fragW3,
                               _Float16* __restrict__ fragDt,
                               _Float16* __restrict__ fragB2) {
  const int gid = blockIdx.x * 256 + threadIdx.x;   // [0, 10240)
  if (gid < 2048) {                                 // fragB8: fp8 16*(W0+W2)
    const int i = gid >> 7, rem = gid & 127, kc = rem >> 6, lane = rem & 63;
    const int n = i * 16 + (lane & 15);
    const int kb = kc * 32 + (lane >> 4) * 8;
    float v[8];
    #pragma unroll
    for (int j = 0; j < 8; ++j)
      v[j] = 16.0f * (attn_w1[(kb + j) * HIDDEN + n] + attn_w1[(128 + kb + j) * HIDDEN + n]);
    int lo = __builtin_amdgcn_cvt_pk_fp8_f32(v[0], v[1], 0, false);
    lo     = __builtin_amdgcn_cvt_pk_fp8_f32(v[2], v[3], lo, true);
    int hi = __builtin_amdgcn_cvt_pk_fp8_f32(v[4], v[5], 0, false);
    hi     = __builtin_amdgcn_cvt_pk_fp8_f32(v[6], v[7], hi, true);
    fragB8[gid] = uint2{(unsigned)lo, (unsigned)hi};
  } else if (gid < 4096) {                          // fragW3: f16 16*W3
    const int g = gid - 2048;
    const int i = g >> 7, rem = g & 127, kc = rem >> 6, lane = rem & 63;
    const int n = i * 16 + (lane & 15);
    const int kb = kc * 32 + (lane >> 4) * 8;
    #pragma unroll
    for (int j = 0; j < 8; ++j)
      fragW3[g * 8 + j] = (_Float16)(16.0f * attn_w1[(192 + kb + j) * HIDDEN + n]);
  } else if (gid < 6144) {                          // fragDt: f16 (W1-W2)^T A-frags
    const int g = gid - 4096;
    const int i = g >> 7, rem = g & 127, kc = rem >> 6, lane = rem & 63;
    const int n = i * 16 + (lane & 15);
    const int kb = kc * 32 + (lane >> 4) * 8;
    #pragma unroll
    for (int j = 0; j < 8; ++j)
      fragDt[g * 8 + j] = (_Float16)(attn_w1[(64 + kb + j) * HIDDEN + n]
                                   - attn_w1[(128 + kb + j) * HIDDEN + n]);
  } else {                                          // fragB2: mlp_w1 f16 A-frags
    const int g = gid - 6144;
    const int nt = g >> 8, kc = (g >> 6) & 3, lane = g & 63;
    const int n = nt * 16 + (lane & 15);
    const int kb = kc * 32 + (lane >> 4) * 8;
    #pragma unroll
    for (int j = 0; j < 8; ++j)
      fragB2[g * 8 + j] = (_Float16)mlp_w1[(kb + j) * HIDDEN + n];
  }
}

// convert user_emb -> fp8(16*emb), 8 elems/thread, fully coalesced
__global__ void din_emb8(const float* __restrict__ user_emb, unsigned char* __restrict__ emb8) {
  const int g = blockIdx.x * 256 + threadIdx.x;     // [0, 800000)
  const int base = g * 8;
  const float4 x = *reinterpret_cast<const float4*>(&user_emb[base]);
  const float4 y = *reinterpret_cast<const float4*>(&user_emb[base + 4]);
  int lo = __builtin_amdgcn_cvt_pk_fp8_f32(16.f * x.x, 16.f * x.y, 0, false);
  lo     = __builtin_amdgcn_cvt_pk_fp8_f32(16.f * x.z, 16.f * x.w, lo, true);
  int hi = __builtin_amdgcn_cvt_pk_fp8_f32(16.f * y.x, 16.f * y.y, 0, false);
  hi     = __builtin_amdgcn_cvt_pk_fp8_f32(16.f * y.z, 16.f * y.w, hi, true);
  *reinterpret_cast<uint2*>(&emb8[base]) = uint2{(unsigned)lo, (unsigned)hi};
}

// ---------------- single fused kernel: one block (512 thr, 8 waves) per row ----------------
__global__ __launch_bounds__(512, 8)
void din_fused_kernel(const int* __restrict__ user_hist,
                      const int* __restrict__ target_item,
                      const float* __restrict__ user_emb,
                      const float* __restrict__ item_emb,
                      const float* __restrict__ attn_b1,
                      const float* __restrict__ attn_w2,
                      const float* __restrict__ mlp_b1,
                      const float* __restrict__ mlp_w2,
                      const float* __restrict__ mlp_b2,
                      const uint2* __restrict__ fragB8,
                      const _Float16* __restrict__ fragW3,
                      const _Float16* __restrict__ fragDt,
                      const _Float16* __restrict__ fragB2,
                      const unsigned char* __restrict__ emb8,   // may be null (ws too small)
                      float* __restrict__ out)
{
  __shared__ __align__(16) uint2 Hf8[MT * 2 * 64];    // 13312 B, fp8(16h) B-frags
  __shared__ __align__(16) _Float16 t16[EMBED];       // 128
  __shared__ int   histL[SEQP];                       // 832
  __shared__ float lp[8][SEQP];                       // 6656
  __shared__ float weights[SEQP];                     // 832
  __shared__ __align__(16) _Float16 mi16[EMBED];      // 128
  __shared__ float red[16];                           // 64
  // total ~22 KB

  const int b    = blockIdx.x;
  const int tid  = threadIdx.x;
  const int lane = tid & 63;
  const int wave = tid >> 6;
  const int m    = lane & 15;
  const int quad = lane >> 4;

  // ---- phase 0: target embedding + hist staging ----
  if (tid < EMBED) t16[tid] = (_Float16)item_emb[target_item[b] * EMBED + tid];
  if (tid < SEQP) histL[tid] = (tid < SEQ) ? user_hist[b * SEQ + tid] : 0;

  // static fp8 weight A-frags (global, independent of LDS)
  long long Aw8[2][2];
  #pragma unroll
  for (int i = 0; i < 2; ++i)
    #pragma unroll
    for (int c = 0; c < 2; ++c)
      Aw8[i][c] = __builtin_bit_cast(long long, fragB8[((2 * wave + i) * 2 + c) * 64 + lane]);
  __syncthreads();

  // ---- phase 1: gather h -> fp8 B-frag LDS ----
  // fast path: emb8 table already holds fp8(16h) -> one 8 B load, no cvt/mul
  if (emb8) {
    for (int slot = tid; slot < MT * 2 * 64; slot += 512) {
      const int ln = slot & 63, kcomb = slot >> 6;
      const int st = kcomb >> 1, kc = kcomb & 1;
      const int s = st * 16 + (ln & 15);
      const int kb = kc * 32 + (ln >> 4) * 8;
      uint2 pv = uint2{0u, 0u};
      if (s < SEQ)
        pv = *reinterpret_cast<const uint2*>(&emb8[histL[s] * EMBED + kb]);
      Hf8[slot] = pv;
    }
  } else {
    for (int slot = tid; slot < MT * 2 * 64; slot += 512) {
      const int ln = slot & 63, kcomb = slot >> 6;
      const int st = kcomb >> 1, kc = kcomb & 1;
      const int s = st * 16 + (ln & 15);
      const int kb = kc * 32 + (ln >> 4) * 8;
      uint2 pv = uint2{0u, 0u};
      if (s < SEQ) {
        const float4* src = reinterpret_cast<const float4*>(&user_emb[histL[s] * EMBED + kb]);
        const float4 x = src[0], y = src[1];
        int lo = __builtin_amdgcn_cvt_pk_fp8_f32(16.f * x.x, 16.f * x.y, 0, false);
        lo     = __builtin_amdgcn_cvt_pk_fp8_f32(16.f * x.z, 16.f * x.w, lo, true);
        int hi = __builtin_amdgcn_cvt_pk_fp8_f32(16.f * y.x, 16.f * y.y, 0, false);
        hi     = __builtin_amdgcn_cvt_pk_fp8_f32(16.f * y.z, 16.f * y.w, hi, true);
        pv = uint2{(unsigned)lo, (unsigned)hi};
      }
      Hf8[slot] = pv;
    }
  }

  // ---- phase 2 (overlaps gather VMEM drain; touches only t16 + global frags) ----
  const f16x8 tv0 = *reinterpret_cast<const f16x8*>(&t16[quad * 8]);
  const f16x8 tv1 = *reinterpret_cast<const f16x8*>(&t16[32 + quad * 8]);

  long long AwT[2][2];
  #pragma unroll
  for (int i = 0; i < 2; ++i) {
    #pragma unroll
    for (int c = 0; c < 2; ++c) {
      const f16x8 w3v = reinterpret_cast<const f16x8*>(fragW3)[((2 * wave + i) * 2 + c) * 64 + lane];
      const f16x8 p = w3v * (c ? tv1 : tv0);
      int lo = __builtin_amdgcn_cvt_pk_fp8_f32((float)p[0], (float)p[1], 0, false);
      lo     = __builtin_amdgcn_cvt_pk_fp8_f32((float)p[2], (float)p[3], lo, true);
      int hi = __builtin_amdgcn_cvt_pk_fp8_f32((float)p[4], (float)p[5], 0, false);
      hi     = __builtin_amdgcn_cvt_pk_fp8_f32((float)p[6], (float)p[7], hi, true);
      AwT[i][c] = __builtin_bit_cast(long long, uint2{(unsigned)lo, (unsigned)hi});
    }
  }

  // c-fold: c[n] = b1[n] + sum_k t[k] D[k][n]; A = D^T frags, B = broadcast t
  float cn[2][4], w2n[2][4];
  #pragma unroll
  for (int i = 0; i < 2; ++i) {
    const int tile = 2 * wave + i;
    const f16x8 d0 = reinterpret_cast<const f16x8*>(fragDt)[(tile * 2 + 0) * 64 + lane];
    const f16x8 d1 = reinterpret_cast<const f16x8*>(fragDt)[(tile * 2 + 1) * 64 + lane];
    f32x4 acc = {0.f, 0.f, 0.f, 0.f};
    acc = __builtin_amdgcn_mfma_f32_16x16x32_f16(d0, tv0, acc, 0, 0, 0);
    acc = __builtin_amdgcn_mfma_f32_16x16x32_f16(d1, tv1, acc, 0, 0, 0);
    const int nb = tile * 16 + quad * 4;
    const float4 b1v = *reinterpret_cast<const float4*>(&attn_b1[nb]);
    const float4 w2v = *reinterpret_cast<const float4*>(&attn_w2[nb]);
    cn[i][0] = 256.0f * (b1v.x + acc[0]);
    cn[i][1] = 256.0f * (b1v.y + acc[1]);
    cn[i][2] = 256.0f * (b1v.z + acc[2]);
    cn[i][3] = 256.0f * (b1v.w + acc[3]);
    w2n[i][0] = w2v.x * (1.0f / 256.0f);
    w2n[i][1] = w2v.y * (1.0f / 256.0f);
    w2n[i][2] = w2v.z * (1.0f / 256.0f);
    w2n[i][3] = w2v.w * (1.0f / 256.0f);
  }
  __syncthreads();

  // ---- phase 3: fp8 K=128 MFMA GEMM (H^T); wave owns n-tiles 2w, 2w+1 ----
  #pragma unroll 2
  for (int st = 0; st < MT; ++st) {
    const long long b0 = __builtin_bit_cast(long long, Hf8[(st * 2 + 0) * 64 + lane]);
    const long long b1 = __builtin_bit_cast(long long, Hf8[(st * 2 + 1) * 64 + lane]);
    float lg = 0.f;
    #pragma unroll
    for (int i = 0; i < 2; ++i) {
      f32x4 acc = {cn[i][0], cn[i][1], cn[i][2], cn[i][3]};
      acc = __builtin_amdgcn_mfma_f32_16x16x32_fp8_fp8(Aw8[i][0], b0, acc, 0, 0, 0);
      acc = __builtin_amdgcn_mfma_f32_16x16x32_fp8_fp8(Aw8[i][1], b1, acc, 0, 0, 0);
      acc = __builtin_amdgcn_mfma_f32_16x16x32_fp8_fp8(AwT[i][0], b0, acc, 0, 0, 0);
      acc = __builtin_amdgcn_mfma_f32_16x16x32_fp8_fp8(AwT[i][1], b1, acc, 0, 0, 0);
      #pragma unroll
      for (int r = 0; r < 4; ++r)
        lg += fmaxf(acc[r], 0.0f) * w2n[i][r];
    }
    lg += __shfl_xor(lg, 16, 64);
    lg += __shfl_xor(lg, 32, 64);
    if (lane < 16) lp[wave][st * 16 + lane] = lg;
  }
  __syncthreads();

  // ---- phase 4: softmax over SEQ on waves 0-3 only (uniform barriers) ----
  float v = -INFINITY, e = 0.0f;
  if (wave < 4) {
    if (tid < SEQ)
      v = lp[0][tid] + lp[1][tid] + lp[2][tid] + lp[3][tid]
        + lp[4][tid] + lp[5][tid] + lp[6][tid] + lp[7][tid];
    float mx = v;
    #pragma unroll
    for (int off = 32; off; off >>= 1) mx = fmaxf(mx, __shfl_xor(mx, off, 64));
    if (lane == 0) red[wave] = mx;
  }
  __syncthreads();
  if (wave < 4) {
    const float mx = fmaxf(fmaxf(red[0], red[1]), fmaxf(red[2], red[3]));
    e = (tid < SEQ) ? expf(v - mx) : 0.0f;
    float ssum = e;
    #pragma unroll
    for (int off = 32; off; off >>= 1) ssum += __shfl_xor(ssum, off, 64);
    if (lane == 0) red[4 + wave] = ssum;
  }
  __syncthreads();
  if (wave < 4) {
    const float tot = red[4] + red[5] + red[6] + red[7];
    if (tid < SEQP) weights[tid] = (tid < SEQ) ? e / tot : 0.0f;
  }
  __syncthreads();

  // ---- phase 5: weighted interest pooling; wave -> (kc = w&1, st-group = w>>1) ----
  {
    const int kc = wave & 1, g = wave >> 1;
    float pk[8];
    #pragma unroll
    for (int j = 0; j < 8; ++j) pk[j] = 0.f;
    #pragma unroll
    for (int st2 = 0; st2 < 4; ++st2) {
      const int st = g + st2 * 4;
      if (st < MT) {
        const float wt = weights[st * 16 + m];
        const uint2 hv = Hf8[(st * 2 + kc) * 64 + lane];
        const f32x2 f0 = __builtin_amdgcn_cvt_pk_f32_fp8((int)hv.x, false);
        const f32x2 f1 = __builtin_amdgcn_cvt_pk_f32_fp8((int)hv.x, true);
        const f32x2 f2 = __builtin_amdgcn_cvt_pk_f32_fp8((int)hv.y, false);
        const f32x2 f3 = __builtin_amdgcn_cvt_pk_f32_fp8((int)hv.y, true);
        pk[0] += wt * f0.x;  pk[1] += wt * f0.y;
        pk[2] += wt * f1.x;  pk[3] += wt * f1.y;
        pk[4] += wt * f2.x;  pk[5] += wt * f2.y;
        pk[6] += wt * f3.x;  pk[7] += wt * f3.y;
      }
    }
    #pragma unroll
    for (int j = 0; j < 8; ++j) {
      float p = pk[j];
      p += __shfl_xor(p, 1, 64);
      p += __shfl_xor(p, 2, 64);
      p += __shfl_xor(p, 4, 64);
      p += __shfl_xor(p, 8, 64);
      pk[j] = p;
    }
    if (m == 0) {
      #pragma unroll
      for (int j = 0; j < 8; ++j)
        lp[g][kc * 32 + quad * 8 + j] = pk[j];     // lp reused: interest partials (16x-scaled)
    }
  }
  __syncthreads();
  if (tid < EMBED)
    mi16[tid] = (_Float16)((lp[0][tid] + lp[1][tid] + lp[2][tid] + lp[3][tid]) * 0.0625f);
  __syncthreads();

  // ---- phase 6: prediction head, f16 MFMA, broadcast-B ----
  {
    const f16x8 mb0 = *reinterpret_cast<const f16x8*>(&mi16[quad * 8]);
    const f16x8 mb1 = *reinterpret_cast<const f16x8*>(&mi16[32 + quad * 8]);
    float z = 0.f;
    #pragma unroll
    for (int i = 0; i < 2; ++i) {
      const f16x8* B2 = reinterpret_cast<const f16x8*>(fragB2) + ((2 * wave + i) * 4) * 64 + lane;
      const int nb = (2 * wave + i) * 16 + quad * 4;
      const float4 bb = *reinterpret_cast<const float4*>(&mlp_b1[nb]);
      const float4 ww = *reinterpret_cast<const float4*>(&mlp_w2[nb]);
      f32x4 acc = {bb.x, bb.y, bb.z, bb.w};
      acc = __builtin_amdgcn_mfma_f32_16x16x32_f16(B2[0],   mb0, acc, 0, 0, 0);
      acc = __builtin_amdgcn_mfma_f32_16x16x32_f16(B2[64],  mb1, acc, 0, 0, 0);
      acc = __builtin_amdgcn_mfma_f32_16x16x32_f16(B2[128], tv0, acc, 0, 0, 0);
      acc = __builtin_amdgcn_mfma_f32_16x16x32_f16(B2[192], tv1, acc, 0, 0, 0);
      z += fmaxf(acc[0], 0.0f) * ww.x;
      z += fmaxf(acc[1], 0.0f) * ww.y;
      z += fmaxf(acc[2], 0.0f) * ww.z;
      z += fmaxf(acc[3], 0.0f) * ww.w;
    }
    z += __shfl_xor(z, 16, 64);
    z += __shfl_xor(z, 32, 64);
    if (lane == 0) red[wave] = z;
  }
  __syncthreads();
  if (tid == 0) {
    const float zz = red[0] + red[1] + red[2] + red[3]
                   + red[4] + red[5] + red[6] + red[7] + mlp_b2[0];
    out[b] = 1.0f / (1.0f + expf(-zz));
  }
}

extern "C" void kernel_launch(void* const* d_in, const int* in_sizes, int n_in,
                              void* d_out, int out_size, void* d_ws, size_t ws_size,
                              hipStream_t stream) {
  const int*   user_hist   = (const int*)  d_in[0];
  const int*   target_item = (const int*)  d_in[1];
  const float* user_emb    = (const float*)d_in[2];
  const float* item_emb    = (const float*)d_in[3];
  const float* attn_w1     = (const float*)d_in[4];
  const float* attn_b1     = (const float*)d_in[5];
  const float* attn_w2     = (const float*)d_in[6];
  // d_in[7] = attn_b2: constant shift on logits -> cancels in softmax
  const float* mlp_w1      = (const float*)d_in[8];
  const float* mlp_b1      = (const float*)d_in[9];
  const float* mlp_w2      = (const float*)d_in[10];
  const float* mlp_b2      = (const float*)d_in[11];
  float* out = (float*)d_out;

  uint2*    fragB8 = (uint2*)d_ws;                           // 16 KB
  _Float16* fragW3 = (_Float16*)((char*)d_ws + 16384);       // 32 KB
  _Float16* fragDt = (_Float16*)((char*)d_ws + 49152);       // 32 KB
  _Float16* fragB2 = (_Float16*)((char*)d_ws + 81920);       // 64 KB
  const size_t emb8_off = 147456;
  const size_t emb8_bytes = (size_t)VOCAB * EMBED;           // 6.4 MB
  unsigned char* emb8 = nullptr;
  if (ws_size >= emb8_off + emb8_bytes)                      // ws_size is call-invariant: capture-safe
    emb8 = (unsigned char*)d_ws + emb8_off;

  din_precompute<<<40, 256, 0, stream>>>(attn_w1, mlp_w1, fragB8, fragW3, fragDt, fragB2);
  if (emb8)
    din_emb8<<<(VOCAB * EMBED / 8 + 255) / 256, 256, 0, stream>>>(user_emb, emb8);

  const int batch = in_sizes[1];
  din_fused_kernel<<<batch, 512, 0, stream>>>(
      user_hist, target_item, user_emb, item_emb,
      attn_b1, attn_w2, mlp_b1, mlp_w2, mlp_b2,
      fragB8, fragW3, fragDt, fragB2, emb8, out);
}